// Round 3
// baseline (533.021 us; speedup 1.0000x reference)
//
#include <hip/hip_runtime.h>
#include <stdint.h>

// ---------------------------------------------------------------------------
// ModifiedSelfAttention (Wan block): QKV GEMM -> RMSNorm+RoPE -> flash attn -> O GEMM
// R2: attn rewritten barrier-free: K/V fragments loaded direct global->VGPR
// (L2-resident), one wave per block, LDS only for the P C->A layout round-trip.
// sm_scale folded into Q at normrope; masked tail tile split out of main loop.
// ---------------------------------------------------------------------------

#define DIM   1536
#define S_TOT 3744
#define NHEAD 12
#define HD    128
#define SM_SCALE 0.08838834764831845f

using short8 = __attribute__((ext_vector_type(8))) short;   // 8 bf16 (4 VGPRs)
using f32x4  = __attribute__((ext_vector_type(4))) float;   // MFMA C/D
using f32x2  = __attribute__((ext_vector_type(2))) float;

__device__ __forceinline__ unsigned short f2bf(float f) {
  unsigned u = __builtin_bit_cast(unsigned, f);
  u += 0x7fffu + ((u >> 16) & 1u);     // RNE
  return (unsigned short)(u >> 16);
}

// async global->LDS, 16B per lane (GEMM staging only)
__device__ __forceinline__ void gl_lds16(const void* g, void* l) {
  auto gp = (const __attribute__((address_space(1))) unsigned int*)g;
  auto lp = (__attribute__((address_space(3))) unsigned int*)(uintptr_t)l;
  __builtin_amdgcn_global_load_lds(gp, lp, 16, 0, 0);
}

// ---------------------------------------------------------------------------
// fp32 -> bf16 convert, all 5 arrays in one launch
// ---------------------------------------------------------------------------
#define NX4 (S_TOT * DIM / 4)
#define NW4 (DIM * DIM / 4)
__global__ __launch_bounds__(256) void cvt5_kernel(
    const float* __restrict__ x, const float* __restrict__ wq,
    const float* __restrict__ wk, const float* __restrict__ wv,
    const float* __restrict__ wo,
    unsigned short* __restrict__ xb, unsigned short* __restrict__ wqb,
    unsigned short* __restrict__ wkb, unsigned short* __restrict__ wvb,
    unsigned short* __restrict__ wob) {
  int gid = blockIdx.x * 256 + threadIdx.x;
  const float* src; unsigned short* dst; int off;
  if (gid < NX4)                { src = x;  dst = xb;  off = gid; }
  else if (gid < NX4 + NW4)     { src = wq; dst = wqb; off = gid - NX4; }
  else if (gid < NX4 + 2 * NW4) { src = wk; dst = wkb; off = gid - NX4 - NW4; }
  else if (gid < NX4 + 3 * NW4) { src = wv; dst = wvb; off = gid - NX4 - 2 * NW4; }
  else if (gid < NX4 + 4 * NW4) { src = wo; dst = wob; off = gid - NX4 - 3 * NW4; }
  else return;
  float4 v = ((const float4*)src)[off];
  ushort4 o;
  o.x = f2bf(v.x); o.y = f2bf(v.y); o.z = f2bf(v.z); o.w = f2bf(v.w);
  ((ushort4*)dst)[off] = o;
}

// ---------------------------------------------------------------------------
// NT GEMM: C[m,n] = sum_k A[m,k]*W[n,k] + bias[n]. m97 structure (proven).
// ---------------------------------------------------------------------------
__device__ __forceinline__ void gemm_body(const unsigned short* __restrict__ A,
                                          const unsigned short* __restrict__ W,
                                          const float* __restrict__ bias,
                                          float* __restrict__ outF,
                                          unsigned short* __restrict__ outB,
                                          int M, int mode) {
  constexpr int K = DIM, N = DIM;
  __shared__ unsigned short As[128 * 32];
  __shared__ unsigned short Ws[128 * 32];
  int tid = threadIdx.x;
  int w = tid >> 6, lane = tid & 63;
  int wr = w >> 1, wc = w & 1, q4 = lane >> 4, ql = lane & 15;
  int m0 = blockIdx.y * 128, n0 = blockIdx.x * 128;

  f32x4 acc[4][4];
  const f32x4 zero4 = {0.f, 0.f, 0.f, 0.f};
#pragma unroll
  for (int i = 0; i < 4; i++)
#pragma unroll
    for (int j = 0; j < 4; j++) acc[i][j] = zero4;

  for (int k0 = 0; k0 < K; k0 += 32) {
    __syncthreads();
#pragma unroll
    for (int r = 0; r < 2; r++) {
      int idx = r * 256 + tid;
      int row = idx >> 2, ch = idx & 3;
      int am = m0 + row; am = (am < M) ? am : (M - 1);
      gl_lds16(A + (size_t)am * K + k0 + ch * 8, &As[idx * 8]);
      gl_lds16(W + (size_t)(n0 + row) * K + k0 + ch * 8, &Ws[idx * 8]);
    }
    __syncthreads();
    short8 af[4], wf[4];
#pragma unroll
    for (int i = 0; i < 4; i++)
      af[i] = *(const short8*)&As[(wr * 64 + i * 16 + ql) * 32 + q4 * 8];
#pragma unroll
    for (int j = 0; j < 4; j++)
      wf[j] = *(const short8*)&Ws[(wc * 64 + j * 16 + ql) * 32 + q4 * 8];
#pragma unroll
    for (int i = 0; i < 4; i++)
#pragma unroll
      for (int j = 0; j < 4; j++)
        acc[i][j] = __builtin_amdgcn_mfma_f32_16x16x32_bf16(af[i], wf[j], acc[i][j], 0, 0, 0);
  }

  float bb[4];
#pragma unroll
  for (int j = 0; j < 4; j++) bb[j] = bias[n0 + wc * 64 + j * 16 + ql];
#pragma unroll
  for (int i = 0; i < 4; i++) {
#pragma unroll
    for (int rg = 0; rg < 4; rg++) {
      int row = m0 + wr * 64 + i * 16 + q4 * 4 + rg;
      if (row < M) {
#pragma unroll
        for (int j = 0; j < 4; j++) {
          int col = n0 + wc * 64 + j * 16 + ql;
          float v = acc[i][j][rg] + bb[j];
          if (mode == 0) outF[(size_t)row * N + col] = v;
          else           outB[(size_t)row * N + col] = f2bf(v);
        }
      }
    }
  }
}

__global__ __launch_bounds__(256) void gemm_qkv_kernel(
    const unsigned short* __restrict__ xb,
    const unsigned short* __restrict__ wqb, const unsigned short* __restrict__ wkb,
    const unsigned short* __restrict__ wvb,
    const float* __restrict__ bq, const float* __restrict__ bk, const float* __restrict__ bv,
    float* __restrict__ Yq, float* __restrict__ Yk, unsigned short* __restrict__ Vb) {
  int z = blockIdx.z;
  const unsigned short* W = (z == 0) ? wqb : ((z == 1) ? wkb : wvb);
  const float* bias       = (z == 0) ? bq  : ((z == 1) ? bk  : bv);
  float* outF             = (z == 0) ? Yq  : Yk;
  gemm_body(xb, W, bias, outF, Vb, S_TOT, (z == 2) ? 1 : 0);
}

__global__ __launch_bounds__(256) void gemm_out_kernel(
    const unsigned short* __restrict__ AO, const unsigned short* __restrict__ wob,
    const float* __restrict__ bo, float* __restrict__ out) {
  gemm_body(AO, wob, bo, out, nullptr, S_TOT, 0);
}

// ---------------------------------------------------------------------------
// RMSNorm + RoPE. Q additionally pre-scaled by HD^-0.5 (folded softmax scale).
// ---------------------------------------------------------------------------
__global__ __launch_bounds__(256) void normrope_kernel(
    const float* __restrict__ Yq, const float* __restrict__ Yk,
    const float* __restrict__ gq, const float* __restrict__ gk,
    const float* __restrict__ freqs,
    unsigned short* __restrict__ Qb, unsigned short* __restrict__ Kb) {
  int s = blockIdx.x;
  int tid = threadIdx.x;
  int w = tid >> 6, lane = tid & 63;
  const f32x2* yq2 = (const f32x2*)(Yq + (size_t)s * DIM);
  const f32x2* yk2 = (const f32x2*)(Yk + (size_t)s * DIM);
  f32x2 vq[3], vk[3];
  float ssq = 0.f, ssk = 0.f;
#pragma unroll
  for (int r = 0; r < 3; r++) {
    int p = tid + 256 * r;
    vq[r] = yq2[p]; vk[r] = yk2[p];
    ssq += vq[r].x * vq[r].x + vq[r].y * vq[r].y;
    ssk += vk[r].x * vk[r].x + vk[r].y * vk[r].y;
  }
#pragma unroll
  for (int d = 1; d < 64; d <<= 1) {
    ssq += __shfl_xor(ssq, d);
    ssk += __shfl_xor(ssk, d);
  }
  __shared__ float rq[4], rk[4];
  if (lane == 0) { rq[w] = ssq; rk[w] = ssk; }
  __syncthreads();
  float tq = rq[0] + rq[1] + rq[2] + rq[3];
  float tk = rk[0] + rk[1] + rk[2] + rk[3];
  float invq = rsqrtf(tq * (1.f / DIM) + 1e-6f);
  float invk = rsqrtf(tk * (1.f / DIM) + 1e-6f);

  int fi = s / (26 * 48);
  int hi = (s / 48) % 26;
  int wi = s % 48;
#pragma unroll
  for (int r = 0; r < 3; r++) {
    int p = tid + 256 * r;
    int c = p & 63;
    int frow = (c < 22) ? fi : ((c < 43) ? hi : wi);
    float ang = freqs[frow * 64 + c];
    float sn, cs;
    __sincosf(ang, &sn, &cs);
    {
      float a = vq[r].x * invq * gq[2 * p];
      float b = vq[r].y * invq * gq[2 * p + 1];
      ushort2 o;
      o.x = f2bf((a * cs - b * sn) * SM_SCALE);
      o.y = f2bf((a * sn + b * cs) * SM_SCALE);
      ((ushort2*)Qb)[(size_t)s * (DIM / 2) + p] = o;
    }
    {
      float a = vk[r].x * invk * gk[2 * p];
      float b = vk[r].y * invk * gk[2 * p + 1];
      ushort2 o; o.x = f2bf(a * cs - b * sn); o.y = f2bf(a * sn + b * cs);
      ((ushort2*)Kb)[(size_t)s * (DIM / 2) + p] = o;
    }
  }
}

// ---------------------------------------------------------------------------
// V transpose (unchanged, proven)
// ---------------------------------------------------------------------------
__global__ __launch_bounds__(256) void vtrans_kernel(const unsigned short* __restrict__ Vb,
                                                     unsigned short* __restrict__ Vt) {
  int d0 = blockIdx.x * 64, s0 = blockIdx.y * 64;
  __shared__ unsigned short t[64][65];
  int tid = threadIdx.x;
#pragma unroll
  for (int r = 0; r < 4; r++) {
    int idx = r * 256 + tid;
    int sr = idx >> 4, c4 = (idx & 15) * 4;
    ushort4 v; v.x = v.y = v.z = v.w = 0;
    int s = s0 + sr;
    if (s < S_TOT) v = *(const ushort4*)(Vb + (size_t)s * DIM + d0 + c4);
    t[sr][c4 + 0] = v.x; t[sr][c4 + 1] = v.y; t[sr][c4 + 2] = v.z; t[sr][c4 + 3] = v.w;
  }
  __syncthreads();
#pragma unroll
  for (int r = 0; r < 4; r++) {
    int idx = r * 256 + tid;
    int dr = idx >> 4, s4 = (idx & 15) * 4;
    if (s0 + s4 < S_TOT) {
      ushort4 v;
      v.x = t[s4 + 0][dr]; v.y = t[s4 + 1][dr]; v.z = t[s4 + 2][dr]; v.w = t[s4 + 3][dr];
      *(ushort4*)(Vt + (size_t)(d0 + dr) * S_TOT + s0 + s4) = v;
    }
  }
}

// ---------------------------------------------------------------------------
// Flash attention v3: barrier-free. One wave per block, 32 q per wave.
// K A-frags and V^T B-frags loaded DIRECTLY global->VGPR (16B, 64B-segmented,
// L2-resident: per-head K+V = 3.7 MB shared by 117 q-waves). LDS only holds
// the per-wave P round-trip (C-layout -> A-layout). No __syncthreads anywhere.
// Main tiles unmasked; tail tile handled by a templated masked clone.
// ---------------------------------------------------------------------------
template <bool MASKED>
__device__ __forceinline__ void attn_tile(
    int k0, int seqlen,
    const unsigned short* __restrict__ Kbase,   // Kb + h*HD (row stride DIM)
    const unsigned short* __restrict__ Vbase,   // Vt + h*HD*S_TOT (row stride S_TOT)
    short8 (&qf)[2][4], f32x4 (&o)[2][8], float (&m_run)[2], float (&l_run)[2],
    unsigned short* __restrict__ Pl, int q4, int ql) {
  const f32x4 zero4 = {0.f, 0.f, 0.f, 0.f};

  // ---- QK^T: S^T[key][q] ; A = K fragment direct from global ----
  f32x4 st[4][2];
#pragma unroll
  for (int mt = 0; mt < 4; mt++) {
    int krow = k0 + mt * 16 + ql;
    if (MASKED) krow = (krow < S_TOT) ? krow : (S_TOT - 1);
    const unsigned short* kp = Kbase + (size_t)krow * DIM + q4 * 8;
    st[mt][0] = zero4; st[mt][1] = zero4;
#pragma unroll
    for (int ks = 0; ks < 4; ks++) {
      short8 kf = *(const short8*)(kp + ks * 32);
      st[mt][0] = __builtin_amdgcn_mfma_f32_16x16x32_bf16(kf, qf[0][ks], st[mt][0], 0, 0, 0);
      st[mt][1] = __builtin_amdgcn_mfma_f32_16x16x32_bf16(kf, qf[1][ks], st[mt][1], 0, 0, 0);
    }
  }

  // ---- online softmax per 16-q half (scores pre-scaled via Q) ----
#pragma unroll
  for (int qh = 0; qh < 2; qh++) {
    float sc[16];
    float mloc = -3.0e38f;
#pragma unroll
    for (int mt = 0; mt < 4; mt++)
#pragma unroll
      for (int rg = 0; rg < 4; rg++) {
        float v = st[mt][qh][rg];
        if (MASKED) {
          int key = k0 + mt * 16 + q4 * 4 + rg;
          v = (key < seqlen) ? v : -3.0e38f;
        }
        sc[mt * 4 + rg] = v;
        mloc = fmaxf(mloc, v);
      }
    mloc = fmaxf(mloc, __shfl_xor(mloc, 16));
    mloc = fmaxf(mloc, __shfl_xor(mloc, 32));
    float mnew = fmaxf(m_run[qh], mloc);
    float alpha = __expf(m_run[qh] - mnew);
    m_run[qh] = mnew;
    float lloc = 0.f;
#pragma unroll
    for (int mt = 0; mt < 4; mt++) {
      float p0 = __expf(sc[mt * 4 + 0] - mnew);   // masked: exp(-inf)=0
      float p1 = __expf(sc[mt * 4 + 1] - mnew);
      float p2 = __expf(sc[mt * 4 + 2] - mnew);
      float p3 = __expf(sc[mt * 4 + 3] - mnew);
      lloc += p0 + p1 + p2 + p3;
      ushort4 pk;
      pk.x = f2bf(p0); pk.y = f2bf(p1); pk.z = f2bf(p2); pk.w = f2bf(p3);
      *(ushort4*)&Pl[(qh * 16 + ql) * 72 + mt * 16 + q4 * 4] = pk;
    }
    lloc += __shfl_xor(lloc, 16);
    lloc += __shfl_xor(lloc, 32);
    l_run[qh] = l_run[qh] * alpha + lloc;
    // rescale O rows (row q = q4*4+rg) by alpha via cross-lane broadcast
#pragma unroll
    for (int rg = 0; rg < 4; rg++) {
      float a = __shfl(alpha, q4 * 4 + rg);
#pragma unroll
      for (int nt = 0; nt < 8; nt++) o[qh][nt][rg] *= a;
    }
  }

  // ---- PV: O[q][d] += P.V ; B = V^T fragment direct from global ----
#pragma unroll
  for (int ks2 = 0; ks2 < 2; ks2++) {
    short8 pa0 = *(const short8*)&Pl[(0 * 16 + ql) * 72 + ks2 * 32 + q4 * 8];
    short8 pa1 = *(const short8*)&Pl[(1 * 16 + ql) * 72 + ks2 * 32 + q4 * 8];
    int kc = k0 + ks2 * 32 + q4 * 8;
    if (MASKED) kc = (kc < S_TOT - 8) ? kc : (S_TOT - 8);   // dup reads; P=0 masks
#pragma unroll
    for (int nt = 0; nt < 8; nt++) {
      short8 vb = *(const short8*)(Vbase + (size_t)(nt * 16 + ql) * S_TOT + kc);
      o[0][nt] = __builtin_amdgcn_mfma_f32_16x16x32_bf16(pa0, vb, o[0][nt], 0, 0, 0);
      o[1][nt] = __builtin_amdgcn_mfma_f32_16x16x32_bf16(pa1, vb, o[1][nt], 0, 0, 0);
    }
  }
}

__global__ __launch_bounds__(64, 2) void attn_kernel(
    const unsigned short* __restrict__ Qb, const unsigned short* __restrict__ Kb,
    const unsigned short* __restrict__ Vt, unsigned short* __restrict__ AO,
    const int* __restrict__ seq_lens) {
  int h = blockIdx.y;
  int lane = threadIdx.x;               // one wave per block
  int q4 = lane >> 4, ql = lane & 15;
  int seqlen = seq_lens[0];
  if (seqlen > S_TOT) seqlen = S_TOT;
  if (seqlen < 1) seqlen = 1;

  __shared__ unsigned short Pl[32 * 72];   // 4.6 KB: P round-trip only

  int q0 = blockIdx.x * 32;                // grid.x = 117 exact (3744/32)
  const unsigned short* Kbase = Kb + (size_t)h * HD;
  const unsigned short* Vbase = Vt + (size_t)h * HD * S_TOT;

  // Q B-frags for both halves (n=lane&15 -> q, k=(lane>>4)*8+j)
  short8 qf[2][4];
#pragma unroll
  for (int qh = 0; qh < 2; qh++) {
    int qrow = q0 + qh * 16 + ql;
#pragma unroll
    for (int ks = 0; ks < 4; ks++)
      qf[qh][ks] = *(const short8*)(Qb + (size_t)qrow * DIM + h * HD + ks * 32 + q4 * 8);
  }

  f32x4 o[2][8];
  const f32x4 zero4 = {0.f, 0.f, 0.f, 0.f};
#pragma unroll
  for (int qh = 0; qh < 2; qh++)
#pragma unroll
    for (int nt = 0; nt < 8; nt++) o[qh][nt] = zero4;
  float m_run[2] = {-3.0e38f, -3.0e38f}, l_run[2] = {0.f, 0.f};

  int ntiles = (S_TOT + 63) / 64;          // 59
  int nfull = seqlen >> 6;                 // fully-valid tiles
  if (nfull > ntiles) nfull = ntiles;

  int kt = 0;
  for (; kt < nfull; kt++)
    attn_tile<false>(kt * 64, seqlen, Kbase, Vbase, qf, o, m_run, l_run, Pl, q4, ql);
  for (; kt < ntiles; kt++)
    attn_tile<true>(kt * 64, seqlen, Kbase, Vbase, qf, o, m_run, l_run, Pl, q4, ql);

  // epilogue
  float linv0 = 1.0f / l_run[0], linv1 = 1.0f / l_run[1];
#pragma unroll
  for (int qh = 0; qh < 2; qh++) {
    float linv = qh ? linv1 : linv0;
#pragma unroll
    for (int rg = 0; rg < 4; rg++) {
      float il = __shfl(linv, q4 * 4 + rg);
      int row = q0 + qh * 16 + q4 * 4 + rg;
#pragma unroll
      for (int nt = 0; nt < 8; nt++)
        AO[(size_t)row * DIM + h * HD + nt * 16 + ql] = f2bf(o[qh][nt][rg] * il);
    }
  }
}

// ---------------------------------------------------------------------------
extern "C" void kernel_launch(void* const* d_in, const int* in_sizes, int n_in,
                              void* d_out, int out_size, void* d_ws, size_t ws_size,
                              hipStream_t stream) {
  const float* x    = (const float*)d_in[0];
  const float* wq   = (const float*)d_in[1];
  const float* bq   = (const float*)d_in[2];
  const float* wk   = (const float*)d_in[3];
  const float* bk   = (const float*)d_in[4];
  const float* wv   = (const float*)d_in[5];
  const float* bv   = (const float*)d_in[6];
  const float* wo   = (const float*)d_in[7];
  const float* bo   = (const float*)d_in[8];
  const float* gq   = (const float*)d_in[9];
  const float* gk   = (const float*)d_in[10];
  const float* freqs = (const float*)d_in[11];
  const int*   seq  = (const int*)d_in[12];

  char* ws = (char*)d_ws;
  const size_t SZ_X = (size_t)S_TOT * DIM * 2;   // bf16 [S,DIM]
  const size_t SZ_W = (size_t)DIM * DIM * 2;     // bf16 [DIM,DIM]
  const size_t SZ_Y = (size_t)S_TOT * DIM * 4;   // fp32 [S,DIM]

  unsigned short* xb  = (unsigned short*)(ws);
  unsigned short* wqb = (unsigned short*)(ws + SZ_X);
  unsigned short* wkb = (unsigned short*)(ws + SZ_X + SZ_W);
  unsigned short* wvb = (unsigned short*)(ws + SZ_X + 2 * SZ_W);
  unsigned short* wob = (unsigned short*)(ws + SZ_X + 3 * SZ_W);
  float*          Yq  = (float*)(ws + SZ_X + 4 * SZ_W);
  float*          Yk  = (float*)(ws + SZ_X + 4 * SZ_W + SZ_Y);
  unsigned short* Vb  = (unsigned short*)(ws + SZ_X + 4 * SZ_W + 2 * SZ_Y);
  unsigned short* Qb  = (unsigned short*)(ws + SZ_X + 4 * SZ_W + 2 * SZ_Y + SZ_X);
  unsigned short* Kb  = (unsigned short*)(ws + SZ_X + 4 * SZ_W + 2 * SZ_Y + 2 * SZ_X);
  unsigned short* Vt  = (unsigned short*)(ws + SZ_X + 4 * SZ_W + 2 * SZ_Y + 3 * SZ_X);
  unsigned short* AO  = (unsigned short*)(ws + SZ_X + 4 * SZ_W + 2 * SZ_Y + 4 * SZ_X);

  int total4 = NX4 + 4 * NW4;
  cvt5_kernel<<<dim3((total4 + 255) / 256), 256, 0, stream>>>(
      x, wq, wk, wv, wo, xb, wqb, wkb, wvb, wob);

  gemm_qkv_kernel<<<dim3(DIM / 128, (S_TOT + 127) / 128, 3), 256, 0, stream>>>(
      xb, wqb, wkb, wvb, bq, bk, bv, Yq, Yk, Vb);

  normrope_kernel<<<dim3(S_TOT), 256, 0, stream>>>(Yq, Yk, gq, gk, freqs, Qb, Kb);

  vtrans_kernel<<<dim3(DIM / 64, (S_TOT + 63) / 64), 256, 0, stream>>>(Vb, Vt);

  attn_kernel<<<dim3(S_TOT / 32, NHEAD), 64, 0, stream>>>(Qb, Kb, Vt, AO, seq);

  gemm_out_kernel<<<dim3(DIM / 128, (S_TOT + 127) / 128), 256, 0, stream>>>(
      AO, wob, bo, (float*)d_out);
}

// Round 4
// 491.879 us; speedup vs baseline: 1.0836x; 1.0836x over previous
//
#include <hip/hip_runtime.h>
#include <stdint.h>

// ---------------------------------------------------------------------------
// ModifiedSelfAttention (Wan block): QKV GEMM -> RMSNorm+RoPE -> flash attn -> O GEMM
// R4: attn = split-K(x2) flash decode. 2 waves x 32q per block; K staged via
// global_load_lds DMA (XOR-swizzled); V fragments loaded EARLY into VGPRs at
// tile top (the pre-barrier vmcnt(0) drain doubles as prefetch completion);
// partial (O', m, l) fp32 -> combine kernel. Qb pre-scaled by HD^-0.5.
// ---------------------------------------------------------------------------

#define DIM   1536
#define S_TOT 3744
#define NHEAD 12
#define HD    128
#define SNH   (S_TOT * NHEAD)
#define SM_SCALE 0.08838834764831845f

using short8 = __attribute__((ext_vector_type(8))) short;   // 8 bf16 (4 VGPRs)
using f32x4  = __attribute__((ext_vector_type(4))) float;   // MFMA C/D
using f32x2  = __attribute__((ext_vector_type(2))) float;

__device__ __forceinline__ unsigned short f2bf(float f) {
  unsigned u = __builtin_bit_cast(unsigned, f);
  u += 0x7fffu + ((u >> 16) & 1u);     // RNE
  return (unsigned short)(u >> 16);
}

// async global->LDS, 16B per lane. LDS dest must be wave-uniform base + lane*16.
__device__ __forceinline__ void gl_lds16(const void* g, void* l) {
  auto gp = (const __attribute__((address_space(1))) unsigned int*)g;
  auto lp = (__attribute__((address_space(3))) unsigned int*)(uintptr_t)l;
  __builtin_amdgcn_global_load_lds(gp, lp, 16, 0, 0);
}

// ---------------------------------------------------------------------------
// fp32 -> bf16 convert, all 5 arrays in one launch
// ---------------------------------------------------------------------------
#define NX4 (S_TOT * DIM / 4)
#define NW4 (DIM * DIM / 4)
__global__ __launch_bounds__(256) void cvt5_kernel(
    const float* __restrict__ x, const float* __restrict__ wq,
    const float* __restrict__ wk, const float* __restrict__ wv,
    const float* __restrict__ wo,
    unsigned short* __restrict__ xb, unsigned short* __restrict__ wqb,
    unsigned short* __restrict__ wkb, unsigned short* __restrict__ wvb,
    unsigned short* __restrict__ wob) {
  int gid = blockIdx.x * 256 + threadIdx.x;
  const float* src; unsigned short* dst; int off;
  if (gid < NX4)                { src = x;  dst = xb;  off = gid; }
  else if (gid < NX4 + NW4)     { src = wq; dst = wqb; off = gid - NX4; }
  else if (gid < NX4 + 2 * NW4) { src = wk; dst = wkb; off = gid - NX4 - NW4; }
  else if (gid < NX4 + 3 * NW4) { src = wv; dst = wvb; off = gid - NX4 - 2 * NW4; }
  else if (gid < NX4 + 4 * NW4) { src = wo; dst = wob; off = gid - NX4 - 3 * NW4; }
  else return;
  float4 v = ((const float4*)src)[off];
  ushort4 o;
  o.x = f2bf(v.x); o.y = f2bf(v.y); o.z = f2bf(v.z); o.w = f2bf(v.w);
  ((ushort4*)dst)[off] = o;
}

// ---------------------------------------------------------------------------
// NT GEMM: C[m,n] = sum_k A[m,k]*W[n,k] + bias[n]. m97 structure (proven).
// ---------------------------------------------------------------------------
__device__ __forceinline__ void gemm_body(const unsigned short* __restrict__ A,
                                          const unsigned short* __restrict__ W,
                                          const float* __restrict__ bias,
                                          float* __restrict__ outF,
                                          unsigned short* __restrict__ outB,
                                          int M, int mode) {
  constexpr int K = DIM, N = DIM;
  __shared__ unsigned short As[128 * 32];
  __shared__ unsigned short Ws[128 * 32];
  int tid = threadIdx.x;
  int w = tid >> 6, lane = tid & 63;
  int wr = w >> 1, wc = w & 1, q4 = lane >> 4, ql = lane & 15;
  int m0 = blockIdx.y * 128, n0 = blockIdx.x * 128;

  f32x4 acc[4][4];
  const f32x4 zero4 = {0.f, 0.f, 0.f, 0.f};
#pragma unroll
  for (int i = 0; i < 4; i++)
#pragma unroll
    for (int j = 0; j < 4; j++) acc[i][j] = zero4;

  for (int k0 = 0; k0 < K; k0 += 32) {
    __syncthreads();
#pragma unroll
    for (int r = 0; r < 2; r++) {
      int idx = r * 256 + tid;
      int row = idx >> 2, ch = idx & 3;
      int am = m0 + row; am = (am < M) ? am : (M - 1);
      gl_lds16(A + (size_t)am * K + k0 + ch * 8, &As[idx * 8]);
      gl_lds16(W + (size_t)(n0 + row) * K + k0 + ch * 8, &Ws[idx * 8]);
    }
    __syncthreads();
    short8 af[4], wf[4];
#pragma unroll
    for (int i = 0; i < 4; i++)
      af[i] = *(const short8*)&As[(wr * 64 + i * 16 + ql) * 32 + q4 * 8];
#pragma unroll
    for (int j = 0; j < 4; j++)
      wf[j] = *(const short8*)&Ws[(wc * 64 + j * 16 + ql) * 32 + q4 * 8];
#pragma unroll
    for (int i = 0; i < 4; i++)
#pragma unroll
      for (int j = 0; j < 4; j++)
        acc[i][j] = __builtin_amdgcn_mfma_f32_16x16x32_bf16(af[i], wf[j], acc[i][j], 0, 0, 0);
  }

  float bb[4];
#pragma unroll
  for (int j = 0; j < 4; j++) bb[j] = bias[n0 + wc * 64 + j * 16 + ql];
#pragma unroll
  for (int i = 0; i < 4; i++) {
#pragma unroll
    for (int rg = 0; rg < 4; rg++) {
      int row = m0 + wr * 64 + i * 16 + q4 * 4 + rg;
      if (row < M) {
#pragma unroll
        for (int j = 0; j < 4; j++) {
          int col = n0 + wc * 64 + j * 16 + ql;
          float v = acc[i][j][rg] + bb[j];
          if (mode == 0) outF[(size_t)row * N + col] = v;
          else           outB[(size_t)row * N + col] = f2bf(v);
        }
      }
    }
  }
}

__global__ __launch_bounds__(256) void gemm_qkv_kernel(
    const unsigned short* __restrict__ xb,
    const unsigned short* __restrict__ wqb, const unsigned short* __restrict__ wkb,
    const unsigned short* __restrict__ wvb,
    const float* __restrict__ bq, const float* __restrict__ bk, const float* __restrict__ bv,
    float* __restrict__ Yq, float* __restrict__ Yk, unsigned short* __restrict__ Vb) {
  int z = blockIdx.z;
  const unsigned short* W = (z == 0) ? wqb : ((z == 1) ? wkb : wvb);
  const float* bias       = (z == 0) ? bq  : ((z == 1) ? bk  : bv);
  float* outF             = (z == 0) ? Yq  : Yk;
  gemm_body(xb, W, bias, outF, Vb, S_TOT, (z == 2) ? 1 : 0);
}

__global__ __launch_bounds__(256) void gemm_out_kernel(
    const unsigned short* __restrict__ AO, const unsigned short* __restrict__ wob,
    const float* __restrict__ bo, float* __restrict__ out) {
  gemm_body(AO, wob, bo, out, nullptr, S_TOT, 0);
}

// ---------------------------------------------------------------------------
// RMSNorm + RoPE. Q additionally pre-scaled by HD^-0.5 (folded softmax scale).
// ---------------------------------------------------------------------------
__global__ __launch_bounds__(256) void normrope_kernel(
    const float* __restrict__ Yq, const float* __restrict__ Yk,
    const float* __restrict__ gq, const float* __restrict__ gk,
    const float* __restrict__ freqs,
    unsigned short* __restrict__ Qb, unsigned short* __restrict__ Kb) {
  int s = blockIdx.x;
  int tid = threadIdx.x;
  int w = tid >> 6, lane = tid & 63;
  const f32x2* yq2 = (const f32x2*)(Yq + (size_t)s * DIM);
  const f32x2* yk2 = (const f32x2*)(Yk + (size_t)s * DIM);
  f32x2 vq[3], vk[3];
  float ssq = 0.f, ssk = 0.f;
#pragma unroll
  for (int r = 0; r < 3; r++) {
    int p = tid + 256 * r;
    vq[r] = yq2[p]; vk[r] = yk2[p];
    ssq += vq[r].x * vq[r].x + vq[r].y * vq[r].y;
    ssk += vk[r].x * vk[r].x + vk[r].y * vk[r].y;
  }
#pragma unroll
  for (int d = 1; d < 64; d <<= 1) {
    ssq += __shfl_xor(ssq, d);
    ssk += __shfl_xor(ssk, d);
  }
  __shared__ float rq[4], rk[4];
  if (lane == 0) { rq[w] = ssq; rk[w] = ssk; }
  __syncthreads();
  float tq = rq[0] + rq[1] + rq[2] + rq[3];
  float tk = rk[0] + rk[1] + rk[2] + rk[3];
  float invq = rsqrtf(tq * (1.f / DIM) + 1e-6f);
  float invk = rsqrtf(tk * (1.f / DIM) + 1e-6f);

  int fi = s / (26 * 48);
  int hi = (s / 48) % 26;
  int wi = s % 48;
#pragma unroll
  for (int r = 0; r < 3; r++) {
    int p = tid + 256 * r;
    int c = p & 63;
    int frow = (c < 22) ? fi : ((c < 43) ? hi : wi);
    float ang = freqs[frow * 64 + c];
    float sn, cs;
    __sincosf(ang, &sn, &cs);
    {
      float a = vq[r].x * invq * gq[2 * p];
      float b = vq[r].y * invq * gq[2 * p + 1];
      ushort2 o;
      o.x = f2bf((a * cs - b * sn) * SM_SCALE);
      o.y = f2bf((a * sn + b * cs) * SM_SCALE);
      ((ushort2*)Qb)[(size_t)s * (DIM / 2) + p] = o;
    }
    {
      float a = vk[r].x * invk * gk[2 * p];
      float b = vk[r].y * invk * gk[2 * p + 1];
      ushort2 o; o.x = f2bf(a * cs - b * sn); o.y = f2bf(a * sn + b * cs);
      ((ushort2*)Kb)[(size_t)s * (DIM / 2) + p] = o;
    }
  }
}

// ---------------------------------------------------------------------------
// V transpose (unchanged, proven)
// ---------------------------------------------------------------------------
__global__ __launch_bounds__(256) void vtrans_kernel(const unsigned short* __restrict__ Vb,
                                                     unsigned short* __restrict__ Vt) {
  int d0 = blockIdx.x * 64, s0 = blockIdx.y * 64;
  __shared__ unsigned short t[64][65];
  int tid = threadIdx.x;
#pragma unroll
  for (int r = 0; r < 4; r++) {
    int idx = r * 256 + tid;
    int sr = idx >> 4, c4 = (idx & 15) * 4;
    ushort4 v; v.x = v.y = v.z = v.w = 0;
    int s = s0 + sr;
    if (s < S_TOT) v = *(const ushort4*)(Vb + (size_t)s * DIM + d0 + c4);
    t[sr][c4 + 0] = v.x; t[sr][c4 + 1] = v.y; t[sr][c4 + 2] = v.z; t[sr][c4 + 3] = v.w;
  }
  __syncthreads();
#pragma unroll
  for (int r = 0; r < 4; r++) {
    int idx = r * 256 + tid;
    int dr = idx >> 4, s4 = (idx & 15) * 4;
    if (s0 + s4 < S_TOT) {
      ushort4 v;
      v.x = t[s4 + 0][dr]; v.y = t[s4 + 1][dr]; v.z = t[s4 + 2][dr]; v.w = t[s4 + 3][dr];
      *(ushort4*)(Vt + (size_t)(d0 + dr) * S_TOT + s0 + s4) = v;
    }
  }
}

// ---------------------------------------------------------------------------
// Flash attention v4: split-K(2). Block = 2 waves x 32q; 64-key tiles.
// K staged via DMA (XOR swizzle); V frags loaded early into regs (prefetch
// completed by the barrier's vmcnt drain). Partials (O',m,l) fp32 out.
// ---------------------------------------------------------------------------
__global__ __launch_bounds__(128, 2) void attn_kernel(
    const unsigned short* __restrict__ Qb, const unsigned short* __restrict__ Kb,
    const unsigned short* __restrict__ Vt,
    float* __restrict__ Op0, float* __restrict__ Op1, float* __restrict__ Ml,
    const int* __restrict__ seq_lens) {
  int h = blockIdx.y, z = blockIdx.z;
  int tid = threadIdx.x;
  int w = tid >> 6, lane = tid & 63;
  int q4 = lane >> 4, ql = lane & 15;
  int seqlen = seq_lens[0];
  if (seqlen > S_TOT) seqlen = S_TOT;
  if (seqlen < 1) seqlen = 1;

  __shared__ unsigned short Kl[64 * 128];    // 16 KB, XOR-swizzled chunks
  __shared__ unsigned short Pl[2][32 * 72];  // 9.2 KB per-wave P round-trip

  int q0 = blockIdx.x * 64 + w * 32;
  bool wact = (q0 < S_TOT);

  const unsigned short* Kbase = Kb + (size_t)h * HD;
  const unsigned short* Vbase = Vt + (size_t)h * HD * S_TOT;

  // Q B-frags (n=lane&15 -> q, k=(lane>>4)*8+j), rows clamped for tail waves
  short8 qf[2][4];
#pragma unroll
  for (int qh = 0; qh < 2; qh++) {
    int qrow = q0 + qh * 16 + ql; if (qrow > S_TOT - 1) qrow = S_TOT - 1;
#pragma unroll
    for (int ks = 0; ks < 4; ks++)
      qf[qh][ks] = *(const short8*)(Qb + (size_t)qrow * DIM + h * HD + ks * 32 + q4 * 8);
  }

  f32x4 o[2][8];
  const f32x4 zero4 = {0.f, 0.f, 0.f, 0.f};
#pragma unroll
  for (int qh = 0; qh < 2; qh++)
#pragma unroll
    for (int nt = 0; nt < 8; nt++) o[qh][nt] = zero4;
  float m_run[2] = {-3.0e38f, -3.0e38f}, l_run[2] = {0.f, 0.f};

  int t0 = z ? 30 : 0, t1 = z ? 59 : 30;   // 59 tiles total (3744/64=58.5)
  for (int kt = t0; kt < t1; kt++) {
    int k0 = kt * 64;
    bool masked = (k0 + 64 > seqlen);      // wave-uniform
    __syncthreads();                       // prev tile's Kl reads done
    // ---- K tile DMA (slot c holds chunk c^(row&15)) ----
#pragma unroll
    for (int r = 0; r < 8; r++) {
      int idx = r * 128 + tid;
      int row = idx >> 4, c = idx & 15;
      int g = c ^ (row & 15);
      // rows >= S_TOT land in the adjacent ws buffer (finite bf16), masked below
      gl_lds16(Kbase + (size_t)(k0 + row) * DIM + g * 8, &Kl[idx * 8]);
    }
    // ---- V frags early -> regs (consumed at PV, latency fully hidden) ----
    short8 vb[2][8];
#pragma unroll
    for (int ks2 = 0; ks2 < 2; ks2++) {
      int kc = k0 + ks2 * 32 + q4 * 8;
      if (masked && kc > S_TOT - 8) kc = S_TOT - 8;   // dup reads; P=0 masks
#pragma unroll
      for (int nt = 0; nt < 8; nt++)
        vb[ks2][nt] = *(const short8*)(Vbase + (size_t)(nt * 16 + ql) * S_TOT + kc);
    }
    __builtin_amdgcn_sched_barrier(0);     // pin: loads issued before compute
    __syncthreads();                       // vmcnt drain -> Kl + vb ready
    if (!wact) continue;

    // ---- QK^T: S^T[key][q] ----
    f32x4 st[4][2];
#pragma unroll
    for (int mt = 0; mt < 4; mt++) {
      st[mt][0] = zero4; st[mt][1] = zero4;
#pragma unroll
      for (int ks = 0; ks < 4; ks++) {
        int c = (ks * 4 + q4) ^ ql;        // un-swizzle (row&15 == ql)
        short8 kf = *(const short8*)&Kl[(mt * 16 + ql) * 128 + c * 8];
        st[mt][0] = __builtin_amdgcn_mfma_f32_16x16x32_bf16(kf, qf[0][ks], st[mt][0], 0, 0, 0);
        st[mt][1] = __builtin_amdgcn_mfma_f32_16x16x32_bf16(kf, qf[1][ks], st[mt][1], 0, 0, 0);
      }
    }

    // ---- online softmax per 16-q half ----
#pragma unroll
    for (int qh = 0; qh < 2; qh++) {
      float sc[16];
      float mloc = -3.0e38f;
#pragma unroll
      for (int mt = 0; mt < 4; mt++)
#pragma unroll
        for (int rg = 0; rg < 4; rg++) {
          float v = st[mt][qh][rg];
          if (masked) {
            int key = k0 + mt * 16 + q4 * 4 + rg;
            v = (key < seqlen) ? v : -3.0e38f;
          }
          sc[mt * 4 + rg] = v;
          mloc = fmaxf(mloc, v);
        }
      mloc = fmaxf(mloc, __shfl_xor(mloc, 16));
      mloc = fmaxf(mloc, __shfl_xor(mloc, 32));
      float mnew = fmaxf(m_run[qh], mloc);
      float alpha = __expf(m_run[qh] - mnew);
      m_run[qh] = mnew;
      float lloc = 0.f;
#pragma unroll
      for (int mt = 0; mt < 4; mt++) {
        float p0, p1, p2, p3;
        if (masked) {
          int kb = k0 + mt * 16 + q4 * 4;
          p0 = (kb + 0 < seqlen) ? __expf(sc[mt * 4 + 0] - mnew) : 0.f;
          p1 = (kb + 1 < seqlen) ? __expf(sc[mt * 4 + 1] - mnew) : 0.f;
          p2 = (kb + 2 < seqlen) ? __expf(sc[mt * 4 + 2] - mnew) : 0.f;
          p3 = (kb + 3 < seqlen) ? __expf(sc[mt * 4 + 3] - mnew) : 0.f;
        } else {
          p0 = __expf(sc[mt * 4 + 0] - mnew);
          p1 = __expf(sc[mt * 4 + 1] - mnew);
          p2 = __expf(sc[mt * 4 + 2] - mnew);
          p3 = __expf(sc[mt * 4 + 3] - mnew);
        }
        lloc += p0 + p1 + p2 + p3;
        ushort4 pk;
        pk.x = f2bf(p0); pk.y = f2bf(p1); pk.z = f2bf(p2); pk.w = f2bf(p3);
        *(ushort4*)&Pl[w][(qh * 16 + ql) * 72 + mt * 16 + q4 * 4] = pk;
      }
      lloc += __shfl_xor(lloc, 16);
      lloc += __shfl_xor(lloc, 32);
      l_run[qh] = l_run[qh] * alpha + lloc;
      // O-rescale via cross-lane broadcast (no LDS)
#pragma unroll
      for (int rg = 0; rg < 4; rg++) {
        float a = __shfl(alpha, q4 * 4 + rg);
#pragma unroll
        for (int nt = 0; nt < 8; nt++) o[qh][nt][rg] *= a;
      }
    }

    // ---- PV from register-resident V ----
#pragma unroll
    for (int ks2 = 0; ks2 < 2; ks2++) {
      short8 pa0 = *(const short8*)&Pl[w][(0 * 16 + ql) * 72 + ks2 * 32 + q4 * 8];
      short8 pa1 = *(const short8*)&Pl[w][(1 * 16 + ql) * 72 + ks2 * 32 + q4 * 8];
#pragma unroll
      for (int nt = 0; nt < 8; nt++) {
        o[0][nt] = __builtin_amdgcn_mfma_f32_16x16x32_bf16(pa0, vb[ks2][nt], o[0][nt], 0, 0, 0);
        o[1][nt] = __builtin_amdgcn_mfma_f32_16x16x32_bf16(pa1, vb[ks2][nt], o[1][nt], 0, 0, 0);
      }
    }
  }

  // ---- partial epilogue: unnormalized O' + (m, l) ----
  if (wact) {
    float* Op = z ? Op1 : Op0;
#pragma unroll
    for (int qh = 0; qh < 2; qh++) {
#pragma unroll
      for (int rg = 0; rg < 4; rg++) {
        int row = q0 + qh * 16 + q4 * 4 + rg;
        if (row < S_TOT) {
#pragma unroll
          for (int nt = 0; nt < 8; nt++)
            Op[(size_t)row * DIM + h * HD + nt * 16 + ql] = o[qh][nt][rg];
        }
      }
    }
    if (lane < 16) {
      int row0 = q0 + lane;
      if (row0 < S_TOT) {
        Ml[(2 * z + 0) * SNH + row0 * NHEAD + h] = m_run[0];
        Ml[(2 * z + 1) * SNH + row0 * NHEAD + h] = l_run[0];
      }
      int row1 = q0 + 16 + lane;
      if (row1 < S_TOT) {
        Ml[(2 * z + 0) * SNH + row1 * NHEAD + h] = m_run[1];
        Ml[(2 * z + 1) * SNH + row1 * NHEAD + h] = l_run[1];
      }
    }
  }
}

// ---------------------------------------------------------------------------
// Split-K combine: AO = (O0'*e^{m0-m} + O1'*e^{m1-m}) / (l0*e^{m0-m}+l1*e^{m1-m})
// ---------------------------------------------------------------------------
__global__ __launch_bounds__(256) void combine_kernel(
    const float* __restrict__ Op0, const float* __restrict__ Op1,
    const float* __restrict__ Ml, unsigned short* __restrict__ AO) {
  int idx = blockIdx.x * 256 + threadIdx.x;   // float4 units
  if (idx >= S_TOT * DIM / 4) return;
  int s = idx / (DIM / 4);
  int rem = idx - s * (DIM / 4);
  int h = rem / (HD / 4);
  float m0 = Ml[0 * SNH + s * NHEAD + h];
  float l0 = Ml[1 * SNH + s * NHEAD + h];
  float m1 = Ml[2 * SNH + s * NHEAD + h];
  float l1 = Ml[3 * SNH + s * NHEAD + h];
  float m = fmaxf(m0, m1);
  float w0 = __expf(m0 - m), w1 = __expf(m1 - m);
  float inv = 1.0f / (l0 * w0 + l1 * w1);
  w0 *= inv; w1 *= inv;
  float4 a = ((const float4*)Op0)[idx];
  float4 b = ((const float4*)Op1)[idx];
  ushort4 ov;
  ov.x = f2bf(a.x * w0 + b.x * w1);
  ov.y = f2bf(a.y * w0 + b.y * w1);
  ov.z = f2bf(a.z * w0 + b.z * w1);
  ov.w = f2bf(a.w * w0 + b.w * w1);
  ((ushort4*)AO)[idx] = ov;
}

// ---------------------------------------------------------------------------
extern "C" void kernel_launch(void* const* d_in, const int* in_sizes, int n_in,
                              void* d_out, int out_size, void* d_ws, size_t ws_size,
                              hipStream_t stream) {
  const float* x    = (const float*)d_in[0];
  const float* wq   = (const float*)d_in[1];
  const float* bq   = (const float*)d_in[2];
  const float* wk   = (const float*)d_in[3];
  const float* bk   = (const float*)d_in[4];
  const float* wv   = (const float*)d_in[5];
  const float* bv   = (const float*)d_in[6];
  const float* wo   = (const float*)d_in[7];
  const float* bo   = (const float*)d_in[8];
  const float* gq   = (const float*)d_in[9];
  const float* gk   = (const float*)d_in[10];
  const float* freqs = (const float*)d_in[11];
  const int*   seq  = (const int*)d_in[12];

  char* ws = (char*)d_ws;
  const size_t SZ_X = (size_t)S_TOT * DIM * 2;   // bf16 [S,DIM]
  const size_t SZ_W = (size_t)DIM * DIM * 2;     // bf16 [DIM,DIM]
  const size_t SZ_Y = (size_t)S_TOT * DIM * 4;   // fp32 [S,DIM]

  unsigned short* xb  = (unsigned short*)(ws);
  unsigned short* wqb = (unsigned short*)(ws + SZ_X);
  unsigned short* wkb = (unsigned short*)(ws + SZ_X + SZ_W);
  unsigned short* wvb = (unsigned short*)(ws + SZ_X + 2 * SZ_W);
  unsigned short* wob = (unsigned short*)(ws + SZ_X + 3 * SZ_W);
  float*          Yq  = (float*)(ws + SZ_X + 4 * SZ_W);               // also Op0
  float*          Yk  = (float*)(ws + SZ_X + 4 * SZ_W + SZ_Y);        // also Op1
  unsigned short* Vb  = (unsigned short*)(ws + SZ_X + 4 * SZ_W + 2 * SZ_Y);
  unsigned short* Qb  = (unsigned short*)(ws + SZ_X + 4 * SZ_W + 2 * SZ_Y + SZ_X);
  unsigned short* Kb  = (unsigned short*)(ws + SZ_X + 4 * SZ_W + 2 * SZ_Y + 2 * SZ_X);
  unsigned short* Vt  = (unsigned short*)(ws + SZ_X + 4 * SZ_W + 2 * SZ_Y + 3 * SZ_X);
  unsigned short* AO  = (unsigned short*)(ws + SZ_X + 4 * SZ_W + 2 * SZ_Y + 4 * SZ_X);
  float*          Ml  = (float*)(ws + SZ_X + 4 * SZ_W + 2 * SZ_Y + 5 * SZ_X);
  // total ws use ~135 MB

  int total4 = NX4 + 4 * NW4;
  cvt5_kernel<<<dim3((total4 + 255) / 256), 256, 0, stream>>>(
      x, wq, wk, wv, wo, xb, wqb, wkb, wvb, wob);

  gemm_qkv_kernel<<<dim3(DIM / 128, (S_TOT + 127) / 128, 3), 256, 0, stream>>>(
      xb, wqb, wkb, wvb, bq, bk, bv, Yq, Yk, Vb);

  normrope_kernel<<<dim3(S_TOT), 256, 0, stream>>>(Yq, Yk, gq, gk, freqs, Qb, Kb);

  vtrans_kernel<<<dim3(DIM / 64, (S_TOT + 63) / 64), 256, 0, stream>>>(Vb, Vt);

  attn_kernel<<<dim3((S_TOT + 63) / 64, NHEAD, 2), 128, 0, stream>>>(
      Qb, Kb, Vt, Yq, Yk, Ml, seq);

  combine_kernel<<<dim3((S_TOT * DIM / 4 + 255) / 256), 256, 0, stream>>>(
      Yq, Yk, Ml, AO);

  gemm_out_kernel<<<dim3(DIM / 128, (S_TOT + 127) / 128), 256, 0, stream>>>(
      AO, wob, bo, (float*)d_out);
}